// Round 1
// baseline (428.281 us; speedup 1.0000x reference)
//
#include <hip/hip_runtime.h>
#include <math.h>

#define Bb 8
#define Tt 1000
#define NHh 8
#define Dd 64

// ---------------- Kernel A: q,v projection GEMM ----------------
// x:[8000,64]  W:[512,65] (last col bias). Output layout [b][h][t][d].
__global__ __launch_bounds__(256) void qv_gemm_kernel(
    const float* __restrict__ x, const float* __restrict__ wq,
    const float* __restrict__ wv, float* __restrict__ qbuf, float* __restrict__ vbuf)
{
    __shared__ float xs[64][68];
    __shared__ float ws[64][65];
    const int tid = threadIdx.x;
    const int tb = blockIdx.x;          // 0..124 token tiles
    const int cb = blockIdx.y;          // 0..15 col tiles (0..7 q, 8..15 v)
    const float* W = (cb < 8) ? wq : wv;
    float* dst = (cb < 8) ? qbuf : vbuf;
    const int cBase = (cb & 7) * 64;
    const int rowBase = tb * 64;

#pragma unroll
    for (int i = 0; i < 4; ++i) {
        int f4 = tid + i * 256;
        int r = f4 >> 4, c4 = (f4 & 15) << 2;
        *(float4*)&xs[r][c4] = *(const float4*)&x[(rowBase + r) * 64 + c4];
    }
#pragma unroll
    for (int i = 0; i < 16; ++i) {
        int idx = tid + i * 256;
        int c = idx >> 6, k = idx & 63;
        ws[c][k] = W[(cBase + c) * 65 + k];
    }
    __syncthreads();

    const int rg = tid >> 4, cg = tid & 15;
    const int r0 = rg * 4, c0 = cg * 4;
    float acc[4][4];
#pragma unroll
    for (int j = 0; j < 4; ++j) {
        float bias = W[(cBase + c0 + j) * 65 + 64];
#pragma unroll
        for (int i = 0; i < 4; ++i) acc[i][j] = bias;
    }
    for (int k0 = 0; k0 < 64; k0 += 4) {
        float4 a[4];
#pragma unroll
        for (int i = 0; i < 4; ++i) a[i] = *(const float4*)&xs[r0 + i][k0];
#pragma unroll
        for (int j = 0; j < 4; ++j) {
            float b0 = ws[c0 + j][k0 + 0];
            float b1 = ws[c0 + j][k0 + 1];
            float b2 = ws[c0 + j][k0 + 2];
            float b3 = ws[c0 + j][k0 + 3];
#pragma unroll
            for (int i = 0; i < 4; ++i)
                acc[i][j] += a[i].x * b0 + a[i].y * b1 + a[i].z * b2 + a[i].w * b3;
        }
    }
#pragma unroll
    for (int i = 0; i < 4; ++i) {
        int row = rowBase + r0 + i;
        int b = row / Tt, t = row - b * Tt;
        int h = cBase >> 6;
        float4 o; o.x = acc[i][0]; o.y = acc[i][1]; o.z = acc[i][2]; o.w = acc[i][3];
        *(float4*)&dst[(((size_t)(b * NHh + h) * Tt) + t) * Dd + c0] = o;
    }
}

// ---------------- Kernel B: fused L1-attention ----------------
// One block per (qtile64, h, b). num accum in registers across 16 source tiles.
__global__ __launch_bounds__(256) void attn_kernel(
    const float* __restrict__ x, const float* __restrict__ wk,
    const float* __restrict__ qbuf, const float* __restrict__ vbuf,
    float* __restrict__ part)
{
    __shared__ float qT[64][64];   // [w][tq]
    __shared__ float kT[64][64];   // [w][ts]
    __shared__ float vS[64][64];   // [ts][w]
    __shared__ float pS[64][64];   // [ts][tq]
    __shared__ float dred[16][64];

    const int tid = threadIdx.x;
    const int qtile = blockIdx.x, h = blockIdx.y, b = blockIdx.z;
    const int m = tid & 15, n = tid >> 4;
    const int tqr = m * 4;
    const float* qb = qbuf + (size_t)(b * NHh + h) * Tt * Dd;
    const float* vb = vbuf + (size_t)(b * NHh + h) * Tt * Dd;
    const float* xb = x + (size_t)b * Tt * Dd;

    const int ldR = (tid >> 4) * 4;   // 4-row group this thread loads/transposes
    const int ldC = (tid & 15) * 4;   // its 4-col (w) group

    const float4 wk4 = *(const float4*)&wk[h * 64 + ldC];

    // stage q tile transposed (once)
    {
        float4 rq[4];
#pragma unroll
        for (int i = 0; i < 4; ++i) {
            int row = qtile * 64 + ldR + i;
            if (row >= Tt) row = Tt - 1;
            rq[i] = *(const float4*)&qb[(size_t)row * Dd + ldC];
        }
#pragma unroll
        for (int u = 0; u < 4; ++u) {
            float4 t;
            t.x = ((const float*)&rq[0])[u];
            t.y = ((const float*)&rq[1])[u];
            t.z = ((const float*)&rq[2])[u];
            t.w = ((const float*)&rq[3])[u];
            *(float4*)&qT[ldC + u][ldR] = t;
        }
    }

    float num[4][4];
    float dsum[4];
#pragma unroll
    for (int i = 0; i < 4; ++i) {
        dsum[i] = 0.f;
#pragma unroll
        for (int j = 0; j < 4; ++j) num[i][j] = 0.f;
    }

    const float C2 = -0.18033688011112042f;  // -(1/8)*log2(e)

    for (int st = 0; st < 16; ++st) {
        const int s0 = st * 64;
        __syncthreads();   // previous score/PV done with kT/vS/pS
        // stage k (x*wk, transposed) and v (straight)
        {
            float4 rk[4];
#pragma unroll
            for (int i = 0; i < 4; ++i) {
                int row = s0 + ldR + i;
                if (row >= Tt) row = Tt - 1;
                rk[i] = *(const float4*)&xb[(size_t)row * Dd + ldC];
            }
#pragma unroll
            for (int u = 0; u < 4; ++u) {
                float wkc = ((const float*)&wk4)[u];
                float4 t;
                t.x = ((const float*)&rk[0])[u] * wkc;
                t.y = ((const float*)&rk[1])[u] * wkc;
                t.z = ((const float*)&rk[2])[u] * wkc;
                t.w = ((const float*)&rk[3])[u] * wkc;
                *(float4*)&kT[ldC + u][ldR] = t;
            }
#pragma unroll
            for (int i = 0; i < 4; ++i) {
                int f4 = tid + i * 256;
                int r = f4 >> 4, c4 = (f4 & 15) << 2;
                int row = s0 + r;
                if (row >= Tt) row = Tt - 1;
                *(float4*)&vS[r][c4] = *(const float4*)&vb[(size_t)row * Dd + c4];
            }
        }
        __syncthreads();

        // score phase: thread = (tq group m, ts group n)
        const int tsr = n * 4;
        float l1[4][4];
#pragma unroll
        for (int i = 0; i < 4; ++i)
#pragma unroll
            for (int j = 0; j < 4; ++j) l1[i][j] = 0.f;

        for (int w = 0; w < 64; ++w) {
            float4 qa = *(const float4*)&qT[w][tqr];
            float4 kb = *(const float4*)&kT[w][tsr];
            const float* qa_ = (const float*)&qa;
            const float* kb_ = (const float*)&kb;
#pragma unroll
            for (int i = 0; i < 4; ++i)
#pragma unroll
                for (int j = 0; j < 4; ++j)
                    l1[i][j] += fabsf(qa_[i] - kb_[j]);
        }
        float p[4][4];
#pragma unroll
        for (int j = 0; j < 4; ++j) {
            const bool valid = (s0 + tsr + j) < Tt;
#pragma unroll
            for (int i = 0; i < 4; ++i)
                p[i][j] = valid ? __builtin_amdgcn_exp2f(C2 * l1[i][j]) : 0.f;
        }
#pragma unroll
        for (int i = 0; i < 4; ++i)
            dsum[i] += (p[i][0] + p[i][1]) + (p[i][2] + p[i][3]);
#pragma unroll
        for (int j = 0; j < 4; ++j) {
            float4 o; o.x = p[0][j]; o.y = p[1][j]; o.z = p[2][j]; o.w = p[3][j];
            *(float4*)&pS[tsr + j][tqr] = o;
        }
        __syncthreads();

        // PV phase: thread = (tq group m, w group n)
        const int w0 = n * 4;
        for (int ts = 0; ts < 64; ++ts) {
            float4 pv = *(const float4*)&pS[ts][tqr];
            float4 vv = *(const float4*)&vS[ts][w0];
            const float* p_ = (const float*)&pv;
            const float* v_ = (const float*)&vv;
#pragma unroll
            for (int i = 0; i < 4; ++i)
#pragma unroll
                for (int j = 0; j < 4; ++j)
                    num[i][j] += p_[i] * v_[j];
        }
    }

    // denominator reduce (null row contributes +1)
#pragma unroll
    for (int i = 0; i < 4; ++i) dred[n][tqr + i] = dsum[i];
    __syncthreads();
    float den[4];
#pragma unroll
    for (int i = 0; i < 4; ++i) {
        float s = 1.0f;
#pragma unroll
        for (int g = 0; g < 16; ++g) s += dred[g][tqr + i];
        den[i] = s;
    }
    const int w0 = n * 4;
#pragma unroll
    for (int i = 0; i < 4; ++i) {
        int tq = qtile * 64 + tqr + i;
        if (tq < Tt) {
            float inv = 1.0f / den[i];
            float4 o;
            o.x = num[i][0] * inv; o.y = num[i][1] * inv;
            o.z = num[i][2] * inv; o.w = num[i][3] * inv;
            *(float4*)&part[(((size_t)(b * Tt + tq) * NHh) + h) * Dd + w0] = o;
        }
    }
}

// ---------------- Kernel C: head-sum + ReLU + wf projection + residual ----------
__global__ __launch_bounds__(256) void finalize_kernel(
    const float* __restrict__ x, const float* __restrict__ wf,
    const float* __restrict__ part, float* __restrict__ out)
{
    __shared__ float wfs[64][65];
    __shared__ float osh[4][64];
    const int tid = threadIdx.x;
    for (int i = tid; i < 64 * 65; i += 256) wfs[i / 65][i % 65] = wf[i];
    const int wave = tid >> 6, lane = tid & 63;
    const int token = blockIdx.x * 4 + wave;   // 0..7999
    float o = 0.f;
    const float* pt = part + (size_t)token * NHh * Dd;
#pragma unroll
    for (int hh = 0; hh < NHh; ++hh) o += pt[hh * Dd + lane];
    o = fmaxf(o, 0.f);
    osh[wave][lane] = o;
    __syncthreads();
    float acc = wfs[lane][64];    // bias
#pragma unroll 8
    for (int w = 0; w < 64; ++w) acc += wfs[lane][w] * osh[wave][w];
    out[(size_t)token * Dd + lane] = x[(size_t)token * Dd + lane] + acc;
}

extern "C" void kernel_launch(void* const* d_in, const int* in_sizes, int n_in,
                              void* d_out, int out_size, void* d_ws, size_t ws_size,
                              hipStream_t stream)
{
    const float* x  = (const float*)d_in[0];
    const float* wq = (const float*)d_in[1];
    const float* wv = (const float*)d_in[2];
    const float* wk = (const float*)d_in[3];
    const float* wf = (const float*)d_in[4];
    float* out = (float*)d_out;

    float* qbuf = (float*)d_ws;                                // 4.096M floats
    float* vbuf = qbuf + (size_t)Bb * NHh * Tt * Dd;           // 4.096M floats
    float* partb = vbuf + (size_t)Bb * NHh * Tt * Dd;          // 4.096M floats

    qv_gemm_kernel<<<dim3(125, 16), 256, 0, stream>>>(x, wq, wv, qbuf, vbuf);
    attn_kernel<<<dim3(16, NHh, Bb), 256, 0, stream>>>(x, wk, qbuf, vbuf, partb);
    finalize_kernel<<<2000, 256, 0, stream>>>(x, wf, partb, out);
}

// Round 2
// 167.354 us; speedup vs baseline: 2.5591x; 2.5591x over previous
//
#include <hip/hip_runtime.h>
#include <math.h>

#define Bb 8
#define Tt 1000
#define TPAD 1024
#define NHh 8
#define Dd 64

typedef short bf16x8 __attribute__((ext_vector_type(8)));
typedef float f32x4 __attribute__((ext_vector_type(4)));

#define QOFF (-0.3f)
#define QSTEP (0.6f / 256.0f)
#define QINV (256.0f / 0.6f)
// p = exp2(CQ * sad)  where score = -(1/8)*STEP*sad
#define CQ (-0.125f * 1.44269504088896341f * QSTEP)

__device__ __forceinline__ unsigned sad_u8(unsigned a, unsigned b, unsigned c) {
#if __has_builtin(__builtin_amdgcn_sad_u8)
    return __builtin_amdgcn_sad_u8(a, b, c);
#else
    unsigned d;
    asm("v_sad_u8 %0, %1, %2, %3" : "=v"(d) : "v"(a), "v"(b), "v"(c));
    return d;
#endif
}

__device__ __forceinline__ unsigned quant8(float v) {
    float t = (v - QOFF) * QINV + 0.5f;
    t = fminf(fmaxf(t, 0.0f), 255.0f);
    return (unsigned)(int)t;
}

__device__ __forceinline__ unsigned cvt_pk_bf16(float lo, float hi) {
    unsigned r;
    asm("v_cvt_pk_bf16_f32 %0, %1, %2" : "=v"(r) : "v"(lo), "v"(hi));
    return r;
}

__device__ __forceinline__ bf16x8 mkbf(unsigned u0, unsigned u1, unsigned u2, unsigned u3) {
    union { unsigned u[4]; bf16x8 v; } x;
    x.u[0] = u0; x.u[1] = u1; x.u[2] = u2; x.u[3] = u3;
    return x.v;
}

__device__ __forceinline__ bf16x8 bfc(uint4 q) {
    union { uint4 q; bf16x8 v; } x; x.q = q; return x.v;
}

// ---------------- Kernel A: prep ----------------
// cb<8: q GEMM -> qq8 (u8, packed 4/dword, [bh][1024][16]dw)  +  k quantize -> kq8 (same layout)
// cb>=8: v GEMM -> vfrag bf16 B-fragment layout [bh][st][kk*4+n][lane] of 16B
__global__ __launch_bounds__(256) void prep_kernel(
    const float* __restrict__ x, const float* __restrict__ wq,
    const float* __restrict__ wv, const float* __restrict__ wk,
    unsigned* __restrict__ qq8, unsigned* __restrict__ kq8,
    uint4* __restrict__ vfrag)
{
    __shared__ float xs[64][68];
    __shared__ float ws[64][65];
    __shared__ float vS[64][68];
    const int tid = threadIdx.x;
    const int st = blockIdx.x;      // 0..15 token tile within (b)
    const int cb = blockIdx.y;      // 0..15
    const int b  = blockIdx.z;
    const bool isQ = (cb < 8);
    const int h = isQ ? cb : (cb - 8);
    const float* W = isQ ? wq : wv;
    const int cBase = h * 64;
    const int bh = b * NHh + h;

#pragma unroll
    for (int i = 0; i < 4; ++i) {
        int f4 = tid + i * 256;
        int r = f4 >> 4, c4 = (f4 & 15) << 2;
        int row = st * 64 + r; if (row >= Tt) row = Tt - 1;
        *(float4*)&xs[r][c4] = *(const float4*)&x[((size_t)b * Tt + row) * 64 + c4];
    }
#pragma unroll
    for (int i = 0; i < 16; ++i) {
        int idx = tid + i * 256;
        int c = idx >> 6, k = idx & 63;
        ws[c][k] = W[(cBase + c) * 65 + k];
    }
    __syncthreads();

    const int rg = tid >> 4, cg = tid & 15;
    const int r0 = rg * 4, c0 = cg * 4;
    float acc[4][4];
#pragma unroll
    for (int j = 0; j < 4; ++j) {
        float bias = W[(cBase + c0 + j) * 65 + 64];
#pragma unroll
        for (int i = 0; i < 4; ++i) acc[i][j] = bias;
    }
    for (int k0 = 0; k0 < 64; k0 += 4) {
        float4 a[4];
#pragma unroll
        for (int i = 0; i < 4; ++i) a[i] = *(const float4*)&xs[r0 + i][k0];
#pragma unroll
        for (int j = 0; j < 4; ++j) {
            float b0 = ws[c0 + j][k0 + 0];
            float b1 = ws[c0 + j][k0 + 1];
            float b2 = ws[c0 + j][k0 + 2];
            float b3 = ws[c0 + j][k0 + 3];
#pragma unroll
            for (int i = 0; i < 4; ++i)
                acc[i][j] += a[i].x * b0 + a[i].y * b1 + a[i].z * b2 + a[i].w * b3;
        }
    }

    if (isQ) {
        // q -> qq8
#pragma unroll
        for (int i = 0; i < 4; ++i) {
            int t = st * 64 + r0 + i;
            unsigned d = 0u;
            if (t < Tt)
                d = quant8(acc[i][0]) | (quant8(acc[i][1]) << 8) |
                    (quant8(acc[i][2]) << 16) | (quant8(acc[i][3]) << 24);
            qq8[((size_t)bh * TPAD + t) * 16 + cg] = d;
        }
        // k = x*wk[h] -> kq8 : thread handles row tid>>2, 16 w's at (tid&3)*16
        {
            const int r = tid >> 2, c4 = tid & 3;
            const int t = st * 64 + r;
            unsigned kd[4];
            if (t < Tt) {
#pragma unroll
                for (int dw = 0; dw < 4; ++dw) {
                    int w = c4 * 16 + dw * 4;
                    float4 wkv = *(const float4*)&wk[h * 64 + w];
                    kd[dw] = quant8(xs[r][w + 0] * wkv.x) |
                             (quant8(xs[r][w + 1] * wkv.y) << 8) |
                             (quant8(xs[r][w + 2] * wkv.z) << 16) |
                             (quant8(xs[r][w + 3] * wkv.w) << 24);
                }
            } else {
                kd[0] = kd[1] = kd[2] = kd[3] = 0u;
            }
            *(uint4*)&kq8[((size_t)bh * TPAD + t) * 16 + c4 * 4] =
                make_uint4(kd[0], kd[1], kd[2], kd[3]);
        }
    } else {
        // v -> vS -> bf16 fragment layout
#pragma unroll
        for (int i = 0; i < 4; ++i) {
            float4 o; o.x = acc[i][0]; o.y = acc[i][1]; o.z = acc[i][2]; o.w = acc[i][3];
            *(float4*)&vS[r0 + i][c0] = o;
        }
        __syncthreads();
#pragma unroll
        for (int e2 = 0; e2 < 2; ++e2) {
            int ent = tid + e2 * 256;       // 0..511 = kk*256 + n*64 + lane
            int kk = ent >> 8, rem = ent & 255, n = rem >> 6, lane = rem & 63;
            int ts = kk * 32 + ((lane >> 4) << 3);
            int w  = n * 16 + (lane & 15);
            unsigned o[4];
#pragma unroll
            for (int pr = 0; pr < 4; ++pr) {
                int t0 = st * 64 + ts + pr * 2;
                float lo = (t0 < Tt)     ? vS[ts + pr * 2][w]     : 0.0f;
                float hi = (t0 + 1 < Tt) ? vS[ts + pr * 2 + 1][w] : 0.0f;
                o[pr] = cvt_pk_bf16(lo, hi);
            }
            vfrag[(((size_t)bh * 16 + st) * 8 + (kk * 4 + n)) * 64 + lane] =
                make_uint4(o[0], o[1], o[2], o[3]);
        }
    }
}

// ---------------- Kernel B: attention, no LDS, no barriers ----------------
// 1 wave per block; wave computes 16 tq x 64 w for one (b,h).
// lane l: P rows tq = qt*16 + (l&15); ts = tile*64 + kk*32 + (l>>4)*8 + e  (A-frag layout).
__global__ __launch_bounds__(64, 4) void attn_kernel(
    const unsigned* __restrict__ qq8, const unsigned* __restrict__ kq8,
    const uint4* __restrict__ vfrag, float* __restrict__ part)
{
    const int l  = threadIdx.x;
    const int qt = blockIdx.x;      // 0..62
    const int h  = blockIdx.y, b = blockIdx.z;
    const int bh = b * NHh + h;
    const int g  = l >> 4;          // 0..3
    const int m  = l & 15;

    // q row (16 dwords = 64 u8)
    unsigned qv[16];
    {
        const uint4* qp = (const uint4*)(qq8 + ((size_t)bh * TPAD + qt * 16 + m) * 16);
        *(uint4*)&qv[0]  = qp[0];
        *(uint4*)&qv[4]  = qp[1];
        *(uint4*)&qv[8]  = qp[2];
        *(uint4*)&qv[12] = qp[3];
    }

    // k pointer: group g's first row of tile 0 (uint4 units; row = 4 uint4)
    const uint4* kp = (const uint4*)(kq8 + (size_t)bh * TPAD * 16) + g * 8 * 4;
    // v fragments: entry lane l of tile 0; entries stride 64, tiles stride 512
    const uint4* vp = vfrag + (size_t)bh * 16 * 8 * 64 + l;

    f32x4 acc0 = {0.f,0.f,0.f,0.f}, acc1 = acc0, acc2 = acc0, acc3 = acc0;
    float dsum = 0.0f;

    for (int t = 0; t < 16; ++t) {
        // V fragments for this tile (8 x 16B), issue first
        uint4 vf0 = vp[0 * 64], vf1 = vp[1 * 64], vf2 = vp[2 * 64], vf3 = vp[3 * 64];
        uint4 vf4 = vp[4 * 64], vf5 = vp[5 * 64], vf6 = vp[6 * 64], vf7 = vp[7 * 64];

        // scores via SAD
        unsigned accu[16];
#pragma unroll
        for (int kk = 0; kk < 2; ++kk) {
#pragma unroll
            for (int e = 0; e < 8; ++e) {
                uint4 kq[4];
#pragma unroll
                for (int r = 0; r < 4; ++r) kq[r] = kp[(kk * 32 + e) * 4 + r];
                const unsigned* kr = (const unsigned*)kq;
                unsigned s = 0u;
#pragma unroll
                for (int w = 0; w < 16; ++w) s = sad_u8(qv[w], kr[w], s);
                accu[kk * 8 + e] = s;
            }
        }

        // p = exp2(CQ * sad)
        float p[16];
#pragma unroll
        for (int i = 0; i < 16; ++i)
            p[i] = __builtin_amdgcn_exp2f(CQ * (float)accu[i]);
        if (t == 15) {  // mask ts >= 1000 (tile-local ts >= 40)
#pragma unroll
            for (int kk = 0; kk < 2; ++kk)
#pragma unroll
                for (int e = 0; e < 8; ++e)
                    if (kk * 32 + (g << 3) + e >= 40) p[kk * 8 + e] = 0.0f;
        }
#pragma unroll
        for (int i = 0; i < 16; ++i) dsum += p[i];

        // pack p -> bf16 A-fragments (kk=0: e 0..7, kk=1: e 8..15)
        bf16x8 A0 = mkbf(cvt_pk_bf16(p[0], p[1]),  cvt_pk_bf16(p[2], p[3]),
                         cvt_pk_bf16(p[4], p[5]),  cvt_pk_bf16(p[6], p[7]));
        bf16x8 A1 = mkbf(cvt_pk_bf16(p[8], p[9]),  cvt_pk_bf16(p[10], p[11]),
                         cvt_pk_bf16(p[12], p[13]), cvt_pk_bf16(p[14], p[15]));

        acc0 = __builtin_amdgcn_mfma_f32_16x16x32_bf16(A0, bfc(vf0), acc0, 0, 0, 0);
        acc0 = __builtin_amdgcn_mfma_f32_16x16x32_bf16(A1, bfc(vf4), acc0, 0, 0, 0);
        acc1 = __builtin_amdgcn_mfma_f32_16x16x32_bf16(A0, bfc(vf1), acc1, 0, 0, 0);
        acc1 = __builtin_amdgcn_mfma_f32_16x16x32_bf16(A1, bfc(vf5), acc1, 0, 0, 0);
        acc2 = __builtin_amdgcn_mfma_f32_16x16x32_bf16(A0, bfc(vf2), acc2, 0, 0, 0);
        acc2 = __builtin_amdgcn_mfma_f32_16x16x32_bf16(A1, bfc(vf6), acc2, 0, 0, 0);
        acc3 = __builtin_amdgcn_mfma_f32_16x16x32_bf16(A0, bfc(vf3), acc3, 0, 0, 0);
        acc3 = __builtin_amdgcn_mfma_f32_16x16x32_bf16(A1, bfc(vf7), acc3, 0, 0, 0);

        kp += 256;   // 64 rows * 4 uint4
        vp += 512;   // 8 entries * 64 lanes
    }

    // denominator: sum over the 4 lanes sharing (l&15), +1 for the null row
    dsum += __shfl_xor(dsum, 16);
    dsum += __shfl_xor(dsum, 32);
    const float den = 1.0f + dsum;   // valid per lane for tq index m = l&15

    // store: D row = qt*16 + g*4 + j, col w = n*16 + m
#pragma unroll
    for (int j = 0; j < 4; ++j) {
        float dj = __shfl(den, g * 4 + j);
        int row = qt * 16 + g * 4 + j;
        if (row < Tt) {
            float inv = 1.0f / dj;
            float* o = part + (((size_t)b * Tt + row) * NHh + h) * 64 + m;
            o[0]  = acc0[j] * inv;
            o[16] = acc1[j] * inv;
            o[32] = acc2[j] * inv;
            o[48] = acc3[j] * inv;
        }
    }
}

// ---------------- Kernel C: head-sum + ReLU + wf projection + residual ----------
__global__ __launch_bounds__(256) void finalize_kernel(
    const float* __restrict__ x, const float* __restrict__ wf,
    const float* __restrict__ part, float* __restrict__ out)
{
    __shared__ float wfs[64][65];
    __shared__ float osh[4][64];
    const int tid = threadIdx.x;
    for (int i = tid; i < 64 * 65; i += 256) wfs[i / 65][i % 65] = wf[i];
    const int wave = tid >> 6, lane = tid & 63;
    const int token = blockIdx.x * 4 + wave;   // 0..7999
    float o = 0.f;
    const float* pt = part + (size_t)token * NHh * Dd;
#pragma unroll
    for (int hh = 0; hh < NHh; ++hh) o += pt[hh * Dd + lane];
    o = fmaxf(o, 0.f);
    osh[wave][lane] = o;
    __syncthreads();
    float acc = wfs[lane][64];    // bias
#pragma unroll 8
    for (int w = 0; w < 64; ++w) acc += wfs[lane][w] * osh[wave][w];
    out[(size_t)token * Dd + lane] = x[(size_t)token * Dd + lane] + acc;
}

extern "C" void kernel_launch(void* const* d_in, const int* in_sizes, int n_in,
                              void* d_out, int out_size, void* d_ws, size_t ws_size,
                              hipStream_t stream)
{
    const float* x  = (const float*)d_in[0];
    const float* wq = (const float*)d_in[1];
    const float* wv = (const float*)d_in[2];
    const float* wk = (const float*)d_in[3];
    const float* wf = (const float*)d_in[4];
    float* out = (float*)d_out;

    char* base = (char*)d_ws;
    float*    part  = (float*)base;                                   // 16,384,000 B
    unsigned* qq8   = (unsigned*)(base + 16384000);                   //  4,194,304 B
    unsigned* kq8   = (unsigned*)(base + 16384000 + 4194304);         //  4,194,304 B
    uint4*    vfrag = (uint4*)(base + 16384000 + 2 * 4194304);        //  8,388,608 B

    prep_kernel<<<dim3(16, 16, Bb), 256, 0, stream>>>(x, wq, wv, wk, qq8, kq8, vfrag);
    attn_kernel<<<dim3(63, NHh, Bb), 64, 0, stream>>>(qq8, kq8, vfrag, part);
    finalize_kernel<<<2000, 256, 0, stream>>>(x, wf, part, out);
}